// Round 4
// baseline (180.520 us; speedup 1.0000x reference)
//
#include <hip/hip_runtime.h>
#include <stdint.h>

// ---- types ----
typedef __attribute__((ext_vector_type(4))) float   f4;
typedef __attribute__((ext_vector_type(8))) short   short8;   // 8 x bf16 (MFMA A/B frag)
typedef __attribute__((ext_vector_type(4))) float   floatx4;  // MFMA C/D frag
typedef __attribute__((ext_vector_type(4))) unsigned int u32x4;

#define LN2F 0.6931471805599453f

// Problem constants
#define BB 65536
#define SS 512
#define DD 100
// K padded to 128 (4 k-steps of 32 for mfma 16x16x32 bf16)

__device__ __forceinline__ unsigned short f2bf(float f) {
  union { float f; unsigned int u; } v; v.f = f;
  unsigned int u = v.u;
  u += 0x7fffu + ((u >> 16) & 1u);   // RNE
  return (unsigned short)(u >> 16);
}
__device__ __forceinline__ u32x4 pack8(f4 a, f4 b) {
  u32x4 r;
  r.x = (unsigned int)f2bf(a[0]) | ((unsigned int)f2bf(a[1]) << 16);
  r.y = (unsigned int)f2bf(a[2]) | ((unsigned int)f2bf(a[3]) << 16);
  r.z = (unsigned int)f2bf(b[0]) | ((unsigned int)f2bf(b[1]) << 16);
  r.w = (unsigned int)f2bf(b[2]) | ((unsigned int)f2bf(b[3]) << 16);
  return r;
}
// numerically stable softplus(x) = log(1+e^x)
__device__ __forceinline__ float softplus_full(float x) {
  return fmaxf(x, 0.f) + log1pf(expf(-fabsf(x)));
}

// ---------------------------------------------------------------------------
// Kernel 1: gather + convert neg rows into MFMA B-fragment tiled layout in ws.
// Layout: 16B unit index = (sgroup*4 + kstep)*64 + (s&15) + 16*kquad
// Also zero-inits out[0].
// ---------------------------------------------------------------------------
__global__ __launch_bounds__(256) void negprep_k(
    const float* __restrict__ tail_table, const int* __restrict__ neg_idx,
    u32x4* __restrict__ nws, float* __restrict__ out) {
  if (blockIdx.x == 0 && threadIdx.x == 0) out[0] = 0.f;
  int tid = blockIdx.x * 256 + threadIdx.x;          // 32 blocks -> 8192 threads
  int s = tid >> 4, kg = tid & 15, k0 = kg * 8;      // 16 threads per s-row
  int nrow = neg_idx[s];
  const float* np = tail_table + (size_t)nrow * DD;  // rows are 400B = 16B aligned
  f4 a = {0.f,0.f,0.f,0.f}, b = {0.f,0.f,0.f,0.f};
  if (kg < 12)       { a = *(const f4*)(np + k0); b = *(const f4*)(np + k0 + 4); }
  else if (kg == 12) { a = *(const f4*)(np + 96); }   // k 96..99 valid, 100..103 pad
  nws[((s >> 4) * 4 + (kg >> 2)) * 64 + (s & 15) + 16 * (kg & 3)] = pack8(a, b);
}

// ---------------------------------------------------------------------------
// Kernel 2: ALL random gathers live here. 1024 blocks x 256 thr; block owns
// 64 b-rows. 16 lanes per row: gather head row, add rel, compute fp32 pos
// loss vs gathered tail row, pack ex into A-frag layout (LDS-staged so the
// global stores are 4KB-contiguous coalesced), gather bias into bias_g.
// ---------------------------------------------------------------------------
__global__ __launch_bounds__(256, 4) void exprep_k(
    const float* __restrict__ head_table, const float* __restrict__ tail_table,
    const float* __restrict__ rel_vec,   const float* __restrict__ rel_bias,
    const int* __restrict__ head_idx,    const int* __restrict__ tail_idx,
    u32x4* __restrict__ exws, float* __restrict__ bias_g,
    float* __restrict__ out) {
  __shared__ u32x4 stage[1024];   // 4 iters x 256 units = 16KB
  __shared__ float red[4];

  const int t = threadIdx.x;
  const int kg = t & 15, grp = t >> 4, k0 = kg * 8;
  const int T = blockIdx.x;                // tile = block

  // rel cached in registers
  f4 ra = {0,0,0,0}, rb = {0,0,0,0};
  if (kg < 12)       { ra = *(const f4*)(rel_vec + k0); rb = *(const f4*)(rel_vec + k0 + 4); }
  else if (kg == 12) { ra = *(const f4*)(rel_vec + 96); }

  float pos_acc = 0.f;
  #pragma unroll
  for (int i = 0; i < 4; ++i) {
    int R = T * 64 + i * 16 + grp;         // global b-row; rid=grp, p=i
    int hrow = head_idx[R], trow = tail_idx[R];
    const float* hp = head_table + (size_t)hrow * DD;
    const float* tp = tail_table + (size_t)trow * DD;
    f4 a = {0,0,0,0}, b = {0,0,0,0}, ta = {0,0,0,0}, tb = {0,0,0,0};
    if (kg < 12) {
      a  = *(const f4*)(hp + k0);  b  = *(const f4*)(hp + k0 + 4);
      ta = *(const f4*)(tp + k0);  tb = *(const f4*)(tp + k0 + 4);
    } else if (kg == 12) {
      a = *(const f4*)(hp + 96);   ta = *(const f4*)(tp + 96);
    }
    f4 e0 = a + ra, e1 = b + rb;
    // frag chunk for (row R, ks=kg>>2, kq=kg&3) -> LDS staging region i
    stage[i * 256 + (kg >> 2) * 64 + 16 * (kg & 3) + grp] = pack8(e0, e1);
    // fp32 pos dot (16-lane group reduction)
    float d = e0[0]*ta[0] + e0[1]*ta[1] + e0[2]*ta[2] + e0[3]*ta[3]
            + e1[0]*tb[0] + e1[1]*tb[1] + e1[2]*tb[2] + e1[3]*tb[3];
    d += __shfl_xor(d, 1); d += __shfl_xor(d, 2);
    d += __shfl_xor(d, 4); d += __shfl_xor(d, 8);
    if (kg == 0) {
      float bias = rel_bias[trow];
      bias_g[R] = bias;
      pos_acc += softplus_full(-(d + bias));   // -log_sigmoid(pos_logit)
    }
  }
  __syncthreads();
  // coalesced frag store: 4 x 4KB contiguous regions
  #pragma unroll
  for (int i = 0; i < 4; ++i)
    exws[(T * 16 + i * 4) * 64 + t] = stage[i * 256 + t];

  // block-reduce pos partial -> atomic
  int w = t >> 6, lane = t & 63;
  #pragma unroll
  for (int off = 32; off; off >>= 1) pos_acc += __shfl_down(pos_acc, off);
  if (lane == 0) red[w] = pos_acc;
  __syncthreads();
  if (t == 0)
    atomicAdd(out, (red[0] + red[1] + red[2] + red[3]) * (1.0f / (float)BB));
}

// ---------------------------------------------------------------------------
// Kernel 3: pure streaming matmul + epilogue. No LDS, no barrier (except
// final reduce). A-frags and bias read coalesced from ws; B-frags L2-hot.
// 2-half structure keeps VGPR < 128 (R3 proved afr stays register-resident).
// ---------------------------------------------------------------------------
__device__ __attribute__((noinline)) float neg_full_recompute(
    const short8* __restrict__ ef, const short8* __restrict__ nf,
    const float* __restrict__ bias_g, int T, int w, int lane, int quad) {
  float nacc = 0.f;
  for (int h = 0; h < 2; ++h) {
    short8 afr[2][4];
    float  br[2][4];
    for (int m = 0; m < 2; ++m) {
      int mf = h * 2 + m;
      for (int ks = 0; ks < 4; ++ks)
        afr[m][ks] = ef[(T * 16 + mf * 4 + ks) * 64 + lane];
      f4 bv = *(const f4*)(bias_g + T * 64 + mf * 16 + quad * 4);
      for (int r = 0; r < 4; ++r) br[m][r] = bv[r];
    }
    for (int g = 0; g < 8; ++g) {
      int ng = w * 8 + g;
      short8 bfr[4];
      for (int ks = 0; ks < 4; ++ks) bfr[ks] = nf[(ng * 4 + ks) * 64 + lane];
      floatx4 acc[2];
      for (int m = 0; m < 2; ++m) {
        floatx4 c; c[0]=br[m][0]; c[1]=br[m][1]; c[2]=br[m][2]; c[3]=br[m][3];
        acc[m] = c;
      }
      for (int ks = 0; ks < 4; ++ks)
        for (int m = 0; m < 2; ++m)
          acc[m] = __builtin_amdgcn_mfma_f32_16x16x32_bf16(afr[m][ks], bfr[ks], acc[m], 0, 0, 0);
      for (int m = 0; m < 2; ++m)
        for (int r = 0; r < 4; ++r)
          nacc += softplus_full(acc[m][r]);
    }
  }
  return nacc;
}

__global__ __launch_bounds__(256, 4) void negmm_k(
    const u32x4* __restrict__ exws, const float* __restrict__ bias_g,
    const u32x4* __restrict__ nws,  float* __restrict__ out) {
  __shared__ float red[4];
  const int t = threadIdx.x, w = t >> 6, lane = t & 63, quad = lane >> 4;
  const int T = blockIdx.x;
  const short8* ef = (const short8*)exws;
  const short8* nf = (const short8*)nws;

  float sx = 0.f, sxx = 0.f, amax = 0.f;
  #pragma unroll
  for (int h = 0; h < 2; ++h) {
    short8 afr[2][4];
    float  br[2][4];
    #pragma unroll
    for (int m = 0; m < 2; ++m) {
      int mf = h * 2 + m;
      #pragma unroll
      for (int ks = 0; ks < 4; ++ks)
        afr[m][ks] = ef[(T * 16 + mf * 4 + ks) * 64 + lane];   // coalesced 1KB
      f4 bv = *(const f4*)(bias_g + T * 64 + mf * 16 + quad * 4);
      #pragma unroll
      for (int r = 0; r < 4; ++r) br[m][r] = bv[r];
    }
    #pragma unroll 2
    for (int g = 0; g < 8; ++g) {
      int ng = w * 8 + g;
      short8 bfr[4];
      #pragma unroll
      for (int ks = 0; ks < 4; ++ks)
        bfr[ks] = nf[(ng * 4 + ks) * 64 + lane];   // L2-hot
      floatx4 acc[2];
      #pragma unroll
      for (int m = 0; m < 2; ++m) {                // bias folded into C-init
        floatx4 c; c[0]=br[m][0]; c[1]=br[m][1]; c[2]=br[m][2]; c[3]=br[m][3];
        acc[m] = c;
      }
      #pragma unroll
      for (int ks = 0; ks < 4; ++ks)
        #pragma unroll
        for (int m = 0; m < 2; ++m)
          acc[m] = __builtin_amdgcn_mfma_f32_16x16x32_bf16(afr[m][ks], bfr[ks], acc[m], 0, 0, 0);
      #pragma unroll
      for (int m = 0; m < 2; ++m)
        #pragma unroll
        for (int r = 0; r < 4; ++r) {
          float x = acc[m][r];
          sx += x;
          sxx = fmaf(x, x, sxx);
          amax = fmaxf(amax, fabsf(x));            // fabs = input modifier
        }
    }
  }
  // deg-2 Taylor softplus sum over this lane's 128 logits (|x|<0.03 => err<5e-9)
  float nacc = fmaf(sx, 0.5f, fmaf(sxx, 0.125f, 128.f * LN2F));
  if (__ballot(amax < 0.03f) != ~0ULL)
    nacc = neg_full_recompute(ef, nf, bias_g, T, w, lane, quad);  // cold exact path

  #pragma unroll
  for (int off = 32; off; off >>= 1) nacc += __shfl_down(nacc, off);
  if (lane == 0) red[w] = nacc;
  __syncthreads();
  if (t == 0)
    atomicAdd(out, (red[0] + red[1] + red[2] + red[3]) * (1.0f / (float)BB));
}

extern "C" void kernel_launch(void* const* d_in, const int* in_sizes, int n_in,
                              void* d_out, int out_size, void* d_ws, size_t ws_size,
                              hipStream_t stream) {
  const float* head_table = (const float*)d_in[0];
  const float* tail_table = (const float*)d_in[1];
  const float* rel_vec    = (const float*)d_in[2];
  const float* rel_bias   = (const float*)d_in[3];
  const int*   head_idx   = (const int*)d_in[4];
  const int*   tail_idx   = (const int*)d_in[5];
  const int*   neg_idx    = (const int*)d_in[6];
  float* out = (float*)d_out;

  char* ws = (char*)d_ws;
  u32x4* nws    = (u32x4*)ws;                       // 512x128 bf16 = 131072 B
  u32x4* exws   = (u32x4*)(ws + 131072);            // 65536x128 bf16 = 16 MB
  float* bias_g = (float*)(ws + 131072 + (size_t)BB * 256);  // 256 KB

  negprep_k<<<32, 256, 0, stream>>>(tail_table, neg_idx, nws, out);
  exprep_k<<<1024, 256, 0, stream>>>(head_table, tail_table, rel_vec, rel_bias,
                                     head_idx, tail_idx, exws, bias_g, out);
  negmm_k<<<1024, 256, 0, stream>>>((const u32x4*)exws, bias_g, (const u32x4*)nws, out);
}

// Round 5
// 160.140 us; speedup vs baseline: 1.1273x; 1.1273x over previous
//
#include <hip/hip_runtime.h>
#include <stdint.h>

// ---- types ----
typedef __attribute__((ext_vector_type(4))) float   f4;
typedef __attribute__((ext_vector_type(8))) short   short8;   // 8 x bf16 (MFMA A/B frag)
typedef __attribute__((ext_vector_type(4))) float   floatx4;  // MFMA C/D frag
typedef __attribute__((ext_vector_type(4))) unsigned int u32x4;

#define LN2F 0.6931471805599453f

// Problem constants
#define BB 65536
#define SS 512
#define DD 100
// K padded to 128 (4 k-steps of 32 for mfma 16x16x32 bf16)

__device__ __forceinline__ unsigned short f2bf(float f) {
  union { float f; unsigned int u; } v; v.f = f;
  unsigned int u = v.u;
  u += 0x7fffu + ((u >> 16) & 1u);   // RNE
  return (unsigned short)(u >> 16);
}
__device__ __forceinline__ u32x4 pack8(f4 a, f4 b) {
  u32x4 r;
  r.x = (unsigned int)f2bf(a[0]) | ((unsigned int)f2bf(a[1]) << 16);
  r.y = (unsigned int)f2bf(a[2]) | ((unsigned int)f2bf(a[3]) << 16);
  r.z = (unsigned int)f2bf(b[0]) | ((unsigned int)f2bf(b[1]) << 16);
  r.w = (unsigned int)f2bf(b[2]) | ((unsigned int)f2bf(b[3]) << 16);
  return r;
}
// numerically stable softplus(x) = log(1+e^x)
__device__ __forceinline__ float softplus_full(float x) {
  return fmaxf(x, 0.f) + log1pf(expf(-fabsf(x)));
}

// ---------------------------------------------------------------------------
// Kernel 1: gather + convert neg rows into MFMA B-fragment tiled layout in ws.
// Layout: 16B unit index = (sgroup*4 + kstep)*64 + (s&15) + 16*kquad
// Also zero-inits out[0].
// ---------------------------------------------------------------------------
__global__ __launch_bounds__(256) void negprep_k(
    const float* __restrict__ tail_table, const int* __restrict__ neg_idx,
    u32x4* __restrict__ nws, float* __restrict__ out) {
  if (blockIdx.x == 0 && threadIdx.x == 0) out[0] = 0.f;
  int tid = blockIdx.x * 256 + threadIdx.x;          // 32 blocks -> 8192 threads
  int s = tid >> 4, kg = tid & 15, k0 = kg * 8;      // 16 threads per s-row
  int nrow = neg_idx[s];
  const float* np = tail_table + (size_t)nrow * DD;  // rows 400B, 16B aligned
  // unconditional loads: max offset 127 floats; max row base (TV-1)*100 ->
  // (TV-1)*100+127 < (TV+1)*100, in-bounds. Junk lanes masked below.
  f4 a = *(const f4*)(np + k0);
  f4 b = *(const f4*)(np + k0 + 4);
  if (kg > 12)  a = (f4){0.f,0.f,0.f,0.f};
  if (kg >= 12) b = (f4){0.f,0.f,0.f,0.f};
  nws[((s >> 4) * 4 + (kg >> 2)) * 64 + (s & 15) + 16 * (kg & 3)] = pack8(a, b);
}

// ---------------------------------------------------------------------------
// Kernel 2: fused main. 1024 blocks x 256 thr; block owns 64 b-rows x all 512 s.
// Stage 1 is a max-MLP batched gather: every thread issues 16 unconditional
// global_load_dwordx4 (4 rows x head+tail) before any consumption;
// __launch_bounds__(256,4) gives the allocator 128 VGPRs to keep them all in
// flight (R3's VGPR=64 software-MLP cap was the 45.7us wall: 773 GB/s on
// 34.5MB of random gathers = the whole duration). Pos-loss is computed in
// fp32 during the gather. Neg matmul: register-lean 2-half loop, per-group
// ballot-guarded Taylor epilogue with inline unrolled exact fallback (no
// scratch anywhere).
// ---------------------------------------------------------------------------
__global__ __launch_bounds__(256, 4) void keg_main(
    const float* __restrict__ head_table, const float* __restrict__ tail_table,
    const float* __restrict__ rel_vec,   const float* __restrict__ rel_bias,
    const int* __restrict__ head_idx,    const int* __restrict__ tail_idx,
    const u32x4* __restrict__ nws,       float* __restrict__ out) {
  __shared__ u32x4 exA4[1024];   // 64 rows x 128 k, A-frag tiled: 16KB
  __shared__ float bias_s[64];
  __shared__ float red[4];

  const int t = threadIdx.x;
  const int kg = t & 15, rid = t >> 4, k0 = kg * 8;
  const int bbase = blockIdx.x * 64;

  // rel fragments (masked; rel_vec has exactly 100 floats -> conditional)
  f4 ra = {0,0,0,0}, rb = {0,0,0,0};
  if (kg <= 12) ra = *(const f4*)(rel_vec + k0);       // kg==12: rel[96..99]
  if (kg <  12) rb = *(const f4*)(rel_vec + k0 + 4);

  // ---- batched gather: addresses first, then 16 dwordx4 back-to-back ----
  const float* hp[4]; const float* tp[4];
  float biasv[4];
  #pragma unroll
  for (int p = 0; p < 4; ++p) {
    int R = bbase + p * 16 + rid;
    hp[p] = head_table + (size_t)head_idx[R] * DD;
    int trow = tail_idx[R];
    tp[p] = tail_table + (size_t)trow * DD;
    biasv[p] = rel_bias[trow];     // 16 lanes same addr -> broadcast
  }
  f4 ha[4], hb[4], ta[4], tb[4];
  #pragma unroll
  for (int p = 0; p < 4; ++p) {
    // unconditional: offset <= 127 floats past row base stays inside table
    ha[p] = *(const f4*)(hp[p] + k0);
    hb[p] = *(const f4*)(hp[p] + k0 + 4);
    ta[p] = *(const f4*)(tp[p] + k0);
    tb[p] = *(const f4*)(tp[p] + k0 + 4);
  }

  float pos_acc = 0.f;
  #pragma unroll
  for (int p = 0; p < 4; ++p) {
    f4 e0 = ha[p] + ra, e1 = hb[p] + rb;
    if (kg > 12)  e0 = (f4){0.f,0.f,0.f,0.f};   // mask junk lanes
    if (kg >= 12) e1 = (f4){0.f,0.f,0.f,0.f};
    exA4[(p * 4 + (kg >> 2)) * 64 + rid + 16 * (kg & 3)] = pack8(e0, e1);
    // fp32 pos dot; e masked zero kills junk t contributions
    float d = e0[0]*ta[p][0] + e0[1]*ta[p][1] + e0[2]*ta[p][2] + e0[3]*ta[p][3]
            + e1[0]*tb[p][0] + e1[1]*tb[p][1] + e1[2]*tb[p][2] + e1[3]*tb[p][3];
    d += __shfl_xor(d, 1); d += __shfl_xor(d, 2);
    d += __shfl_xor(d, 4); d += __shfl_xor(d, 8);
    if (kg == 0) {
      bias_s[p * 16 + rid] = biasv[p];
      pos_acc += softplus_full(-(d + biasv[p]));   // -log_sigmoid(pos_logit)
    }
  }
  __syncthreads();

  // ---- neg matmul: 2 mf-halves outer (32-VGPR A-frags), 8 s-groups inner ----
  const int w = t >> 6, lane = t & 63, quad = lane >> 4;
  const short8* exAs = (const short8*)exA4;
  const short8* nf   = (const short8*)nws;
  float nacc = 0.f;
  #pragma unroll
  for (int h = 0; h < 2; ++h) {
    short8 afr[2][4];
    float  br[2][4];
    #pragma unroll
    for (int m = 0; m < 2; ++m) {
      int mf = h * 2 + m;
      #pragma unroll
      for (int ks = 0; ks < 4; ++ks) afr[m][ks] = exAs[(mf * 4 + ks) * 64 + lane];
      #pragma unroll
      for (int r = 0; r < 4; ++r)   br[m][r]  = bias_s[mf * 16 + quad * 4 + r];
    }
    #pragma unroll 2
    for (int g = 0; g < 8; ++g) {
      int ng = w * 8 + g;
      short8 bfr[4];
      #pragma unroll
      for (int ks = 0; ks < 4; ++ks)
        bfr[ks] = nf[(ng * 4 + ks) * 64 + lane];   // L2-hot
      floatx4 acc[2];
      #pragma unroll
      for (int m = 0; m < 2; ++m) {                // bias folded into C-init
        floatx4 c; c[0]=br[m][0]; c[1]=br[m][1]; c[2]=br[m][2]; c[3]=br[m][3];
        acc[m] = c;
      }
      #pragma unroll
      for (int ks = 0; ks < 4; ++ks)
        #pragma unroll
        for (int m = 0; m < 2; ++m)
          acc[m] = __builtin_amdgcn_mfma_f32_16x16x32_bf16(afr[m][ks], bfr[ks], acc[m], 0, 0, 0);
      // per-group guarded epilogue (8 logits/lane)
      float s1 = 0.f, s2 = 0.f, gmax = 0.f;
      #pragma unroll
      for (int m = 0; m < 2; ++m)
        #pragma unroll
        for (int r = 0; r < 4; ++r) {
          float x = acc[m][r];
          s1 += x;
          s2 = fmaf(x, x, s2);
          gmax = fmaxf(gmax, fabsf(x));            // fabs = input modifier
        }
      if (__ballot(gmax < 0.03f) == ~0ULL) {
        // deg-2 Taylor softplus: ln2 + x/2 + x^2/8, |err|<5e-9 for |x|<0.03
        nacc += fmaf(s1, 0.5f, fmaf(s2, 0.125f, 8.f * LN2F));
      } else {                                     // inline exact path, no scratch
        #pragma unroll
        for (int m = 0; m < 2; ++m)
          #pragma unroll
          for (int r = 0; r < 4; ++r)
            nacc += softplus_full(acc[m][r]);
      }
    }
  }

  // ---- block reduce -> atomic accumulate (exact pow2 1/BB scale) ----
  float tot = nacc + pos_acc;
  #pragma unroll
  for (int off = 32; off; off >>= 1) tot += __shfl_down(tot, off);
  if (lane == 0) red[w] = tot;
  __syncthreads();
  if (t == 0)
    atomicAdd(out, (red[0] + red[1] + red[2] + red[3]) * (1.0f / (float)BB));
}

extern "C" void kernel_launch(void* const* d_in, const int* in_sizes, int n_in,
                              void* d_out, int out_size, void* d_ws, size_t ws_size,
                              hipStream_t stream) {
  const float* head_table = (const float*)d_in[0];
  const float* tail_table = (const float*)d_in[1];
  const float* rel_vec    = (const float*)d_in[2];
  const float* rel_bias   = (const float*)d_in[3];
  const int*   head_idx   = (const int*)d_in[4];
  const int*   tail_idx   = (const int*)d_in[5];
  const int*   neg_idx    = (const int*)d_in[6];
  float* out = (float*)d_out;

  u32x4* nws = (u32x4*)d_ws;                 // 512 x 128 bf16 = 131072 B

  negprep_k<<<32, 256, 0, stream>>>(tail_table, neg_idx, nws, out);
  keg_main<<<1024, 256, 0, stream>>>(head_table, tail_table, rel_vec, rel_bias,
                                     head_idx, tail_idx, (const u32x4*)nws, out);
}